// Round 3
// baseline (2436.215 us; speedup 1.0000x reference)
//
#include <hip/hip_runtime.h>
#include <stdint.h>

#define TLEN 512
#define HDIM 512
#define DDIM 128
#define NCLS 10

typedef float f32x4 __attribute__((ext_vector_type(4)));
typedef short bf16x8 __attribute__((ext_vector_type(8)));
typedef unsigned long long u64;

__device__ __forceinline__ unsigned short f2bf(float f) {
  union { float f; unsigned u; } v; v.f = f;
  return (unsigned short)((v.u + 0x7FFFu + ((v.u >> 16) & 1u)) >> 16);
}
__device__ __forceinline__ float bf2f(unsigned short h) {
  union { unsigned u; float f; } v; v.u = ((unsigned)h) << 16; return v.f;
}
__device__ __forceinline__ float sigm(float x) {
  return __builtin_amdgcn_rcpf(1.0f + __expf(-x));
}
__device__ __forceinline__ u64 ald(const u64* p) {
  return __hip_atomic_load(p, __ATOMIC_RELAXED, __HIP_MEMORY_SCOPE_AGENT);
}
__device__ __forceinline__ void ast(unsigned* p, unsigned v) {
  __hip_atomic_store(p, v, __ATOMIC_RELAXED, __HIP_MEMORY_SCOPE_AGENT);
}

// ---------------- gate tables: G[g][v][h], g in {f,i,c(pre-sigmoided),o} ----
__global__ void k_gates(const float* __restrict__ emb,
                        const float* __restrict__ Wfx, const float* __restrict__ bf_,
                        const float* __restrict__ Wix, const float* __restrict__ bi_,
                        const float* __restrict__ Wcx, const float* __restrict__ bc_,
                        const float* __restrict__ Wox, const float* __restrict__ bo_,
                        float* __restrict__ G) {
  int tid = blockIdx.x * 256 + threadIdx.x;          // 0..6143
  int h = tid & (HDIM - 1);
  int v = (tid >> 9) % 3;
  int g = tid / (3 * HDIM);
  const float* W; const float* bb;
  if (g == 0)      { W = Wfx; bb = bf_; }
  else if (g == 1) { W = Wix; bb = bi_; }
  else if (g == 2) { W = Wcx; bb = bc_; }
  else             { W = Wox; bb = bo_; }
  const float* e = emb + v * DDIM;
  const float* w = W + h * DDIM;
  float s = bb[h];
  #pragma unroll 8
  for (int d = 0; d < DDIM; ++d) s += e[d] * w[d];
  if (g == 2) s = sigm(s);                           // pre-sigmoid the c-gate
  G[tid] = s;
}

// ---------------- weight pack: register-resident B-fragments ----------------
// pk2: [hs(8)][nt(4)][gate(2)][kt(16)][lane(64)][e(8)] bf16
__global__ void k_pack_fi(const float* __restrict__ Wfh, const float* __restrict__ Wih,
                          unsigned short* __restrict__ pk) {
  int tid = blockIdx.x * 256 + threadIdx.x;          // 0..65535
  int l  = tid & 63;
  int kt = (tid >> 6) & 15;
  int g  = (tid >> 10) & 1;
  int nt = (tid >> 11) & 3;
  int hs = (tid >> 13) & 7;
  int n  = hs * 64 + nt * 16 + (l & 15);
  int k0 = kt * 32 + (l >> 4) * 8;
  const float* src = (g ? Wih : Wfh) + n * HDIM + k0;
  unsigned short* dst = pk + (size_t)tid * 8;
  #pragma unroll
  for (int e = 0; e < 8; ++e) dst[e] = f2bf(src[e]);
}

// pko: [hs(8)][nt(4)][kt(16)][lane(64)][e(8)] bf16
__global__ void k_pack_o(const float* __restrict__ Woh, unsigned short* __restrict__ pk) {
  int tid = blockIdx.x * 256 + threadIdx.x;          // 0..32767
  int l  = tid & 63;
  int kt = (tid >> 6) & 15;
  int nt = (tid >> 10) & 3;
  int hs = (tid >> 12) & 7;
  int n  = hs * 64 + nt * 16 + (l & 15);
  int k0 = kt * 32 + (l >> 4) * 8;
  const float* src = Woh + n * HDIM + k0;
  unsigned short* dst = pk + (size_t)tid * 8;
  #pragma unroll
  for (int e = 0; e < 8; ++e) dst[e] = f2bf(src[e]);
}

// ---------------- scan: 128 WGs = 16 batch-tiles x 8 h-slices ---------------
// Per WG: M=16 rows, N=64 cols, K=512. Weights in regs for all 512 steps.
// c exchanged per step via self-validating tagged words: (t+1)<<16 | bf16(c).
__global__ __launch_bounds__(256, 1)
void k_scan(const int* __restrict__ x, const float* __restrict__ G,
            const unsigned short* __restrict__ pk2,
            const unsigned short* __restrict__ pko,
            unsigned* __restrict__ cbuf,
            unsigned short* __restrict__ hfin) {
  __shared__ float gts[12][68];                      // gate tables for this h-slice
  __shared__ unsigned char xv[16][516];              // token ids, padded
  __shared__ uint4 lds_a[2][16][64];                 // A-frag share, parity dbuf (32 KB)

  const int tid  = threadIdx.x;
  const int lane = tid & 63;
  const int w    = tid >> 6;                         // wave = nt (0..3)
  const int bt   = blockIdx.x & 15;
  const int hs   = blockIdx.x >> 4;

  for (int j = tid; j < 12 * 64; j += 256) {
    int gv = j >> 6, c = j & 63;
    gts[gv][c] = G[gv * HDIM + hs * 64 + c];
  }
  for (int j = tid; j < 16 * TLEN; j += 256) {
    int r = j >> 9, tt = j & (TLEN - 1);
    xv[r][tt] = (unsigned char)x[(bt * 16 + r) * TLEN + tt];
  }

  bf16x8 wf[16], wi[16];
  {
    const bf16x8* ws = (const bf16x8*)pk2 + (size_t)((hs * 4 + w) * 2) * (16 * 64) + lane;
    #pragma unroll
    for (int kt = 0; kt < 16; ++kt) { wf[kt] = ws[kt * 64]; wi[kt] = ws[(16 + kt) * 64]; }
  }

  bf16x8 afr[16];
  #pragma unroll
  for (int kt = 0; kt < 16; ++kt) afr[kt] = bf16x8{0,0,0,0,0,0,0,0};  // c_0 = 0

  float cf[4] = {0.f, 0.f, 0.f, 0.f};
  const int rgrp = (lane >> 4) * 4;                  // C/D row base (batch row)
  const int coll = lane & 15;                        // C/D col (within 16-tile)
  const int col  = w * 16 + coll;                    // h col within slice
  const f32x4 zz = {0.f, 0.f, 0.f, 0.f};

  u64* cb64 = (u64*)cbuf;
  // consumer base (u64 units): + parity*65536 + kt*16 + j
  const int qoff = bt * 4096 + (lane & 15) * 256 + (lane >> 4) * 4;
  // producer base (dword units): + parity*131072 + (rgrp+r)*512
  const int poff = bt * 8192 + hs * 64 + col;
  const u64 msk = 0xFFFF0000FFFF0000ULL;

  __syncthreads();

  for (int t = 0; t < TLEN - 1; ++t) {
    f32x4 af = zz, ai = zz;
    #pragma unroll
    for (int kt = 0; kt < 16; ++kt) {
      af = __builtin_amdgcn_mfma_f32_16x16x32_bf16(afr[kt], wf[kt], af, 0, 0, 0);
      ai = __builtin_amdgcn_mfma_f32_16x16x32_bf16(afr[kt], wi[kt], ai, 0, 0, 0);
    }
    const unsigned tg = (unsigned)(t + 1);
    const int par = (t + 1) & 1;
    const int sbase = par * 131072 + poff;
    #pragma unroll
    for (int r = 0; r < 4; ++r) {
      int vv = xv[rgrp + r][t];
      float fg = sigm(af[r] + gts[0 + vv][col]);
      float ig = sigm(ai[r] + gts[3 + vv][col]);
      float sc = gts[6 + vv][col];                   // pre-sigmoided c-gate
      float cn = sc * ig + cf[r] * fg;
      cf[r] = cn;
      ast(cbuf + sbase + (rgrp + r) * 512, (tg << 16) | (unsigned)f2bf(cn));
    }
    asm volatile("" ::: "memory");                   // keep stores before the spin

    // acquire c_{t+1}: this wave's kt quarter, per-word tag-validated
    const u64 pat = ((u64)tg << 48) | ((u64)tg << 16);
    const u64* qb = cb64 + (size_t)par * 65536 + qoff;
    u64 a[4][4];
    #pragma unroll
    for (int ktl = 0; ktl < 4; ++ktl) {
      const u64* p = qb + (size_t)((w << 2) | ktl) * 16;
      a[ktl][0] = ald(p + 0); a[ktl][1] = ald(p + 1);
      a[ktl][2] = ald(p + 2); a[ktl][3] = ald(p + 3);
    }
    uint4 got[4];
    #pragma unroll
    for (int ktl = 0; ktl < 4; ++ktl) {
      const u64* p = qb + (size_t)((w << 2) | ktl) * 16;
      while ((((a[ktl][0] ^ pat) | (a[ktl][1] ^ pat) |
               (a[ktl][2] ^ pat) | (a[ktl][3] ^ pat)) & msk) != 0ULL) {
        a[ktl][0] = ald(p + 0); a[ktl][1] = ald(p + 1);
        a[ktl][2] = ald(p + 2); a[ktl][3] = ald(p + 3);
      }
      got[ktl].x = (unsigned)(a[ktl][0] & 0xFFFF) | ((unsigned)(a[ktl][0] >> 32) << 16);
      got[ktl].y = (unsigned)(a[ktl][1] & 0xFFFF) | ((unsigned)(a[ktl][1] >> 32) << 16);
      got[ktl].z = (unsigned)(a[ktl][2] & 0xFFFF) | ((unsigned)(a[ktl][2] >> 32) << 16);
      got[ktl].w = (unsigned)(a[ktl][3] & 0xFFFF) | ((unsigned)(a[ktl][3] >> 32) << 16);
    }
    #pragma unroll
    for (int ktl = 0; ktl < 4; ++ktl)
      lds_a[par][(w << 2) | ktl][lane] = got[ktl];
    __syncthreads();
    #pragma unroll
    for (int kt = 0; kt < 16; ++kt) {
      union { uint4 q; bf16x8 v; } u;
      u.q = lds_a[par][kt][lane];
      afr[kt] = u.v;
    }
  }

  // ---- final step t = 511: f, i and o gates; h = tanh(c)*o -----------------
  {
    const int t = TLEN - 1;
    bf16x8 wo[16];
    const bf16x8* os = (const bf16x8*)pko + (size_t)(hs * 4 + w) * (16 * 64) + lane;
    #pragma unroll
    for (int kt = 0; kt < 16; ++kt) wo[kt] = os[kt * 64];
    f32x4 af = zz, ai = zz, ao = zz;
    #pragma unroll
    for (int kt = 0; kt < 16; ++kt) {
      af = __builtin_amdgcn_mfma_f32_16x16x32_bf16(afr[kt], wf[kt], af, 0, 0, 0);
      ai = __builtin_amdgcn_mfma_f32_16x16x32_bf16(afr[kt], wi[kt], ai, 0, 0, 0);
      ao = __builtin_amdgcn_mfma_f32_16x16x32_bf16(afr[kt], wo[kt], ao, 0, 0, 0);
    }
    #pragma unroll
    for (int r = 0; r < 4; ++r) {
      int vv = xv[rgrp + r][t];
      float fg = sigm(af[r] + gts[0 + vv][col]);
      float ig = sigm(ai[r] + gts[3 + vv][col]);
      float sc = gts[6 + vv][col];
      float cn = sc * ig + cf[r] * fg;
      float og = sigm(ao[r] + gts[9 + vv][col]);
      float hv = tanhf(cn) * og;
      hfin[(bt * 16 + rgrp + r) * HDIM + hs * 64 + col] = f2bf(hv);
    }
  }
}

// ---------------- classifier head + log_softmax: one wave per row -----------
__global__ __launch_bounds__(64)
void k_head(const unsigned short* __restrict__ hfin, const float* __restrict__ Wph,
            const float* __restrict__ bp, float* __restrict__ out) {
  const int b = blockIdx.x;
  const int lane = threadIdx.x;
  float acc[NCLS];
  #pragma unroll
  for (int c = 0; c < NCLS; ++c) acc[c] = 0.f;
  const unsigned short* hrow = hfin + (size_t)b * HDIM;
  for (int k = lane; k < HDIM; k += 64) {
    float hv = bf2f(hrow[k]);
    #pragma unroll
    for (int c = 0; c < NCLS; ++c) acc[c] += hv * Wph[c * HDIM + k];
  }
  #pragma unroll
  for (int c = 0; c < NCLS; ++c)
    #pragma unroll
    for (int off = 32; off > 0; off >>= 1)
      acc[c] += __shfl_down(acc[c], off, 64);
  if (lane == 0) {
    float p[NCLS]; float m = -1e30f;
    #pragma unroll
    for (int c = 0; c < NCLS; ++c) { p[c] = acc[c] + bp[c]; m = fmaxf(m, p[c]); }
    float s = 0.f;
    #pragma unroll
    for (int c = 0; c < NCLS; ++c) s += __expf(p[c] - m);
    const float ls = __logf(s);
    #pragma unroll
    for (int c = 0; c < NCLS; ++c) out[b * NCLS + c] = p[c] - m - ls;
  }
}

extern "C" void kernel_launch(void* const* d_in, const int* in_sizes, int n_in,
                              void* d_out, int out_size, void* d_ws, size_t ws_size,
                              hipStream_t stream) {
  const int*   x   = (const int*)d_in[0];
  const float* emb = (const float*)d_in[1];
  const float* Wfx = (const float*)d_in[2];
  const float* Wfh = (const float*)d_in[3];
  const float* bf_ = (const float*)d_in[4];
  const float* Wix = (const float*)d_in[5];
  const float* Wih = (const float*)d_in[6];
  const float* bi_ = (const float*)d_in[7];
  const float* Wox = (const float*)d_in[8];
  const float* Woh = (const float*)d_in[9];
  const float* bo_ = (const float*)d_in[10];
  const float* Wcx = (const float*)d_in[11];
  const float* bc_ = (const float*)d_in[12];
  const float* Wph = (const float*)d_in[13];
  const float* bp_ = (const float*)d_in[14];

  char* ws = (char*)d_ws;
  float*          G    = (float*)(ws);                      // 24 KB   @ 0
  unsigned short* hfin = (unsigned short*)(ws + 32768);     // 256 KB  @ 32K
  unsigned*       cbuf = (unsigned*)(ws + 524288);          // 1 MB    @ 512K
  unsigned short* pk2  = (unsigned short*)(ws + 1572864);   // 1 MB    @ 1.5M
  unsigned short* pko  = (unsigned short*)(ws + 2621440);   // 512 KB  @ 2.5M

  hipMemsetAsync(cbuf, 0, 1048576, stream);                 // clear tags (first-call safety)
  hipLaunchKernelGGL(k_gates,   dim3(24),  dim3(256), 0, stream,
                     emb, Wfx, bf_, Wix, bi_, Wcx, bc_, Wox, bo_, G);
  hipLaunchKernelGGL(k_pack_fi, dim3(256), dim3(256), 0, stream, Wfh, Wih, pk2);
  hipLaunchKernelGGL(k_pack_o,  dim3(128), dim3(256), 0, stream, Woh, pko);
  hipLaunchKernelGGL(k_scan,    dim3(128), dim3(256), 0, stream, x, G, pk2, pko, cbuf, hfin);
  hipLaunchKernelGGL(k_head,    dim3(256), dim3(64),  0, stream, hfin, Wph, bp_, (float*)d_out);
}

// Round 4
// 1468.695 us; speedup vs baseline: 1.6588x; 1.6588x over previous
//
#include <hip/hip_runtime.h>
#include <stdint.h>

#define TLEN 512
#define HDIM 512
#define DDIM 128
#define NCLS 10

typedef float f32x4 __attribute__((ext_vector_type(4)));
typedef short bf16x8 __attribute__((ext_vector_type(8)));
typedef unsigned long long u64;

__device__ __forceinline__ unsigned short f2bf(float f) {
  union { float f; unsigned u; } v; v.f = f;
  return (unsigned short)((v.u + 0x7FFFu + ((v.u >> 16) & 1u)) >> 16);
}
__device__ __forceinline__ float bf2f(unsigned short h) {
  union { unsigned u; float f; } v; v.u = ((unsigned)h) << 16; return v.f;
}
__device__ __forceinline__ float sigm(float x) {
  return __builtin_amdgcn_rcpf(1.0f + __expf(-x));
}
__device__ __forceinline__ u64 ald(const u64* p) {
  return __hip_atomic_load(p, __ATOMIC_RELAXED, __HIP_MEMORY_SCOPE_AGENT);
}
__device__ __forceinline__ void ast16(unsigned short* p, unsigned short v) {
  __hip_atomic_store(p, v, __ATOMIC_RELAXED, __HIP_MEMORY_SCOPE_AGENT);
}
__device__ __forceinline__ void astd(unsigned* p, unsigned v) {
  __hip_atomic_store(p, v, __ATOMIC_RELAXED, __HIP_MEMORY_SCOPE_AGENT);
}

// ---------------- gate tables: G[g][v][h], g in {f,i,c(pre-sigmoided),o} ----
__global__ void k_gates(const float* __restrict__ emb,
                        const float* __restrict__ Wfx, const float* __restrict__ bf_,
                        const float* __restrict__ Wix, const float* __restrict__ bi_,
                        const float* __restrict__ Wcx, const float* __restrict__ bc_,
                        const float* __restrict__ Wox, const float* __restrict__ bo_,
                        float* __restrict__ G) {
  int tid = blockIdx.x * 256 + threadIdx.x;          // 0..6143
  int h = tid & (HDIM - 1);
  int v = (tid >> 9) % 3;
  int g = tid / (3 * HDIM);
  const float* W; const float* bb;
  if (g == 0)      { W = Wfx; bb = bf_; }
  else if (g == 1) { W = Wix; bb = bi_; }
  else if (g == 2) { W = Wcx; bb = bc_; }
  else             { W = Wox; bb = bo_; }
  const float* e = emb + v * DDIM;
  const float* w = W + h * DDIM;
  float s = bb[h];
  #pragma unroll 8
  for (int d = 0; d < DDIM; ++d) s += e[d] * w[d];
  if (g == 2) s = sigm(s);                           // pre-sigmoid the c-gate
  G[tid] = s;
}

// ---------------- weight pack: register-resident B-fragments ----------------
// pk2: [hs(8)][nt(4)][gate(2)][kt(16)][lane(64)][e(8)] bf16
__global__ void k_pack_fi(const float* __restrict__ Wfh, const float* __restrict__ Wih,
                          unsigned short* __restrict__ pk) {
  int tid = blockIdx.x * 256 + threadIdx.x;          // 0..65535
  int l  = tid & 63;
  int kt = (tid >> 6) & 15;
  int g  = (tid >> 10) & 1;
  int nt = (tid >> 11) & 3;
  int hs = (tid >> 13) & 7;
  int n  = hs * 64 + nt * 16 + (l & 15);
  int k0 = kt * 32 + (l >> 4) * 8;
  const float* src = (g ? Wih : Wfh) + n * HDIM + k0;
  unsigned short* dst = pk + (size_t)tid * 8;
  #pragma unroll
  for (int e = 0; e < 8; ++e) dst[e] = f2bf(src[e]);
}

// pko: [hs(8)][nt(4)][kt(16)][lane(64)][e(8)] bf16
__global__ void k_pack_o(const float* __restrict__ Woh, unsigned short* __restrict__ pk) {
  int tid = blockIdx.x * 256 + threadIdx.x;          // 0..32767
  int l  = tid & 63;
  int kt = (tid >> 6) & 15;
  int nt = (tid >> 10) & 3;
  int hs = (tid >> 12) & 7;
  int n  = hs * 64 + nt * 16 + (l & 15);
  int k0 = kt * 32 + (l >> 4) * 8;
  const float* src = Woh + n * HDIM + k0;
  unsigned short* dst = pk + (size_t)tid * 8;
  #pragma unroll
  for (int e = 0; e < 8; ++e) dst[e] = f2bf(src[e]);
}

// ---------------- scan: 128 WGs = 16 batch-tiles x 8 h-slices ---------------
// Per WG: M=16 rows, N=64 cols, K=512. Weights in regs for all 512 steps.
// Exchange: plain [row16][col512] bf16 tile per (parity,bt) + one 64B flag line.
__global__ __launch_bounds__(256, 1)
void k_scan(const int* __restrict__ x, const float* __restrict__ G,
            const unsigned short* __restrict__ pk2,
            const unsigned short* __restrict__ pko,
            char* __restrict__ cbuf, unsigned* __restrict__ flg,
            unsigned short* __restrict__ hfin) {
  __shared__ float gts[12][68];                      // gate tables for this h-slice
  __shared__ unsigned char xv[16][516];              // token ids, padded
  __shared__ uint4 lds_a[16][64];                    // A-frag share (16 KB)

  const int tid  = threadIdx.x;
  const int lane = tid & 63;
  const int w    = tid >> 6;                         // wave = nt (0..3)
  const int bt   = blockIdx.x & 15;
  const int hs   = blockIdx.x >> 4;

  for (int j = tid; j < 12 * 64; j += 256) {
    int gv = j >> 6, c = j & 63;
    gts[gv][c] = G[gv * HDIM + hs * 64 + c];
  }
  for (int j = tid; j < 16 * TLEN; j += 256) {
    int r = j >> 9, tt = j & (TLEN - 1);
    xv[r][tt] = (unsigned char)x[(bt * 16 + r) * TLEN + tt];
  }

  bf16x8 wf[16], wi[16];
  {
    const bf16x8* ws = (const bf16x8*)pk2 + (size_t)((hs * 4 + w) * 2) * (16 * 64) + lane;
    #pragma unroll
    for (int kt = 0; kt < 16; ++kt) { wf[kt] = ws[kt * 64]; wi[kt] = ws[(16 + kt) * 64]; }
  }

  bf16x8 afr[16];
  #pragma unroll
  for (int kt = 0; kt < 16; ++kt) afr[kt] = bf16x8{0,0,0,0,0,0,0,0};  // c_0 = 0

  float cf[4] = {0.f, 0.f, 0.f, 0.f};
  const int rgrp = (lane >> 4) * 4;                  // C/D row base (batch row)
  const int coll = lane & 15;                        // C/D col (within 16-tile)
  const int col  = w * 16 + coll;                    // h col within slice
  const int colb = (hs * 64 + col) * 2;              // byte offset within a row
  const int rowb = (lane & 15) * 1024 + (lane >> 4) * 16; // consumer row/chunk base
  const f32x4 zz = {0.f, 0.f, 0.f, 0.f};

  __syncthreads();

  for (int t = 0; t < TLEN - 1; ++t) {
    f32x4 af = zz, ai = zz;
    #pragma unroll
    for (int kt = 0; kt < 16; ++kt) {
      af = __builtin_amdgcn_mfma_f32_16x16x32_bf16(afr[kt], wf[kt], af, 0, 0, 0);
      ai = __builtin_amdgcn_mfma_f32_16x16x32_bf16(afr[kt], wi[kt], ai, 0, 0, 0);
    }
    const unsigned tg = (unsigned)(t + 1);
    const int par = (int)(tg & 1);
    char* dbase = cbuf + par * 262144 + bt * 16384;

    #pragma unroll
    for (int r = 0; r < 4; ++r) {
      int vv = xv[rgrp + r][t];
      float fg = sigm(af[r] + gts[0 + vv][col]);
      float ig = sigm(ai[r] + gts[3 + vv][col]);
      float sc = gts[6 + vv][col];                   // pre-sigmoided c-gate
      float cn = sc * ig + cf[r] * fg;
      cf[r] = cn;
      ast16((unsigned short*)(dbase + (rgrp + r) * 1024 + colb), f2bf(cn));
    }
    __syncthreads();                                 // all data stores drained (vmcnt 0)

    unsigned* fl = flg + (par * 16 + bt) * 16;       // 64B line, dword per hs
    if (tid == 0) astd(fl + hs, tg);

    const u64 pat2 = ((u64)tg << 32) | (u64)tg;
    const u64* fp = (const u64*)fl;
    u64 g0, g1, g2, g3;
    do {
      g0 = ald(fp + 0); g1 = ald(fp + 1); g2 = ald(fp + 2); g3 = ald(fp + 3);
    } while (((g0 ^ pat2) | (g1 ^ pat2) | (g2 ^ pat2) | (g3 ^ pat2)) != 0ULL);
    asm volatile("" ::: "memory");                   // no data load before flag pass

    // this wave's 4 kt quarters: full 64B lines per row
    const char* rb = dbase + rowb;
    #pragma unroll
    for (int i = 0; i < 4; ++i) {
      const int kt = (w << 2) | i;
      const u64* p = (const u64*)(rb + kt * 64);
      u64 lo = ald(p + 0), hi = ald(p + 1);
      uint4 q;
      q.x = (unsigned)lo; q.y = (unsigned)(lo >> 32);
      q.z = (unsigned)hi; q.w = (unsigned)(hi >> 32);
      lds_a[kt][lane] = q;
    }
    __syncthreads();
    #pragma unroll
    for (int kt = 0; kt < 16; ++kt) {
      union { uint4 q; bf16x8 v; } u;
      u.q = lds_a[kt][lane];
      afr[kt] = u.v;
    }
  }

  // ---- final step t = 511: f, i and o gates; h = tanh(c)*o -----------------
  {
    const int t = TLEN - 1;
    bf16x8 wo[16];
    const bf16x8* os = (const bf16x8*)pko + (size_t)(hs * 4 + w) * (16 * 64) + lane;
    #pragma unroll
    for (int kt = 0; kt < 16; ++kt) wo[kt] = os[kt * 64];
    f32x4 af = zz, ai = zz, ao = zz;
    #pragma unroll
    for (int kt = 0; kt < 16; ++kt) {
      af = __builtin_amdgcn_mfma_f32_16x16x32_bf16(afr[kt], wf[kt], af, 0, 0, 0);
      ai = __builtin_amdgcn_mfma_f32_16x16x32_bf16(afr[kt], wi[kt], ai, 0, 0, 0);
      ao = __builtin_amdgcn_mfma_f32_16x16x32_bf16(afr[kt], wo[kt], ao, 0, 0, 0);
    }
    #pragma unroll
    for (int r = 0; r < 4; ++r) {
      int vv = xv[rgrp + r][t];
      float fg = sigm(af[r] + gts[0 + vv][col]);
      float ig = sigm(ai[r] + gts[3 + vv][col]);
      float sc = gts[6 + vv][col];
      float cn = sc * ig + cf[r] * fg;
      float og = sigm(ao[r] + gts[9 + vv][col]);
      float hv = tanhf(cn) * og;
      hfin[(bt * 16 + rgrp + r) * HDIM + hs * 64 + col] = f2bf(hv);
    }
  }
}

// ---------------- classifier head + log_softmax: one wave per row -----------
__global__ __launch_bounds__(64)
void k_head(const unsigned short* __restrict__ hfin, const float* __restrict__ Wph,
            const float* __restrict__ bp, float* __restrict__ out) {
  const int b = blockIdx.x;
  const int lane = threadIdx.x;
  float acc[NCLS];
  #pragma unroll
  for (int c = 0; c < NCLS; ++c) acc[c] = 0.f;
  const unsigned short* hrow = hfin + (size_t)b * HDIM;
  for (int k = lane; k < HDIM; k += 64) {
    float hv = bf2f(hrow[k]);
    #pragma unroll
    for (int c = 0; c < NCLS; ++c) acc[c] += hv * Wph[c * HDIM + k];
  }
  #pragma unroll
  for (int c = 0; c < NCLS; ++c)
    #pragma unroll
    for (int off = 32; off > 0; off >>= 1)
      acc[c] += __shfl_down(acc[c], off, 64);
  if (lane == 0) {
    float p[NCLS]; float m = -1e30f;
    #pragma unroll
    for (int c = 0; c < NCLS; ++c) { p[c] = acc[c] + bp[c]; m = fmaxf(m, p[c]); }
    float s = 0.f;
    #pragma unroll
    for (int c = 0; c < NCLS; ++c) s += __expf(p[c] - m);
    const float ls = __logf(s);
    #pragma unroll
    for (int c = 0; c < NCLS; ++c) out[b * NCLS + c] = p[c] - m - ls;
  }
}

extern "C" void kernel_launch(void* const* d_in, const int* in_sizes, int n_in,
                              void* d_out, int out_size, void* d_ws, size_t ws_size,
                              hipStream_t stream) {
  const int*   x   = (const int*)d_in[0];
  const float* emb = (const float*)d_in[1];
  const float* Wfx = (const float*)d_in[2];
  const float* Wfh = (const float*)d_in[3];
  const float* bf_ = (const float*)d_in[4];
  const float* Wix = (const float*)d_in[5];
  const float* Wih = (const float*)d_in[6];
  const float* bi_ = (const float*)d_in[7];
  const float* Wox = (const float*)d_in[8];
  const float* Woh = (const float*)d_in[9];
  const float* bo_ = (const float*)d_in[10];
  const float* Wcx = (const float*)d_in[11];
  const float* bc_ = (const float*)d_in[12];
  const float* Wph = (const float*)d_in[13];
  const float* bp_ = (const float*)d_in[14];

  char* ws = (char*)d_ws;
  float*          G    = (float*)(ws);                      // 24 KB   @ 0
  unsigned short* hfin = (unsigned short*)(ws + 32768);     // 256 KB  @ 32K
  char*           cbuf = (char*)(ws + 524288);              // 512 KB  @ 512K (2 par x 16 bt x 16KB)
  unsigned*       flg  = (unsigned*)(ws + 1048576);         // 2 KB    @ 1M
  unsigned short* pk2  = (unsigned short*)(ws + 1114112);   // 1 MB    @ 1M+64K
  unsigned short* pko  = (unsigned short*)(ws + 2162688);   // 512 KB  @ 2M+64K

  hipMemsetAsync(flg, 0, 2048, stream);                     // fresh flags every call
  hipLaunchKernelGGL(k_gates,   dim3(24),  dim3(256), 0, stream,
                     emb, Wfx, bf_, Wix, bi_, Wcx, bc_, Wox, bo_, G);
  hipLaunchKernelGGL(k_pack_fi, dim3(256), dim3(256), 0, stream, Wfh, Wih, pk2);
  hipLaunchKernelGGL(k_pack_o,  dim3(128), dim3(256), 0, stream, Woh, pko);
  hipLaunchKernelGGL(k_scan,    dim3(128), dim3(256), 0, stream, x, G, pk2, pko, cbuf, flg, hfin);
  hipLaunchKernelGGL(k_head,    dim3(256), dim3(64),  0, stream, hfin, Wph, bp_, (float*)d_out);
}